// Round 1
// baseline (171.277 us; speedup 1.0000x reference)
//
#include <hip/hip_runtime.h>
#include <hip/hip_bf16.h>

// TwoHotEmbedding: out[t] = w[i1[t]] + w[i2[t]], except out[t] = w[i1[t]] when i1==i2.
// One 64-lane wave per token; each lane moves one float4 (16B) per row.
// B*S = 65536 tokens, D = 256 floats/row -> 64 lanes x float4 covers a row exactly.

#define EMBED_DIM 256

__global__ __launch_bounds__(256) void TwoHotEmbedding_13030930776069_kernel(
    const int* __restrict__ idx1,
    const int* __restrict__ idx2,
    const float* __restrict__ weight,
    float* __restrict__ out,
    int n_tokens)
{
    const int gtid = blockIdx.x * blockDim.x + threadIdx.x;
    const int wave = gtid >> 6;          // one wave per token
    const int lane = gtid & 63;
    if (wave >= n_tokens) return;

    const int a = idx1[wave];
    const int b = idx2[wave];

    const float4* __restrict__ rowA =
        (const float4*)(weight + (size_t)a * EMBED_DIM);
    const float4* __restrict__ rowB =
        (const float4*)(weight + (size_t)b * EMBED_DIM);

    float4 va = rowA[lane];
    float4 r;
    if (a == b) {
        r = va;                          // scatter-to-same-slot sets 1, not 2
    } else {
        float4 vb = rowB[lane];
        r = make_float4(va.x + vb.x, va.y + vb.y, va.z + vb.z, va.w + vb.w);
    }

    ((float4*)(out + (size_t)wave * EMBED_DIM))[lane] = r;
}

extern "C" void kernel_launch(void* const* d_in, const int* in_sizes, int n_in,
                              void* d_out, int out_size, void* d_ws, size_t ws_size,
                              hipStream_t stream) {
    const int*   idx1   = (const int*)d_in[0];    // input_one [16,4096] int32
    const int*   idx2   = (const int*)d_in[1];    // input_two [16,4096] int32
    const float* weight = (const float*)d_in[2];  // [100000,256] fp32
    float*       out    = (float*)d_out;          // [16,4096,256] fp32

    const int n_tokens = in_sizes[0];             // 65536
    // 4 waves (tokens) per 256-thread block
    const int blocks = (n_tokens + 3) / 4;
    TwoHotEmbedding_13030930776069_kernel<<<blocks, 256, 0, stream>>>(
        idx1, idx2, weight, out, n_tokens);
}